// Round 17
// baseline (485.513 us; speedup 1.0000x reference)
//
#include <hip/hip_runtime.h>
#include <math.h>

#define N_NODES   50000
#define N_EDGES   800000
#define IN_FEAT   64
#define HIDDEN    32
#define GRID_SZ   4
#define N_GRAPHS  128
#define NEG_SLOPE 0.01f
#define SCAN_BLOCKS 196   // ceil(50000/256)
#define NH (N_NODES * HIDDEN)   // 1.6M

// ---------------------------------------------------------------------------
__global__ __launch_bounds__(256) void zero_int_kernel(int* __restrict__ p, int n) {
  const int i = blockIdx.x * 256 + threadIdx.x;
  if (i < n) p[i] = 0;
}

// ---------------------------------------------------------------------------
// CSR build
// ---------------------------------------------------------------------------
__global__ __launch_bounds__(256) void hist_kernel(
    const int* __restrict__ dst, int* __restrict__ deg) {
  const int e = blockIdx.x * 256 + threadIdx.x;
  if (e < N_EDGES) atomicAdd(&deg[dst[e]], 1);
}

__global__ __launch_bounds__(256) void scanA_kernel(
    const int* __restrict__ deg, int* __restrict__ bsum) {
  const int i = blockIdx.x * 256 + threadIdx.x;
  int v = (i < N_NODES) ? deg[i] : 0;
#pragma unroll
  for (int o = 32; o > 0; o >>= 1) v += __shfl_down(v, o, 64);
  __shared__ int ws[4];
  if ((threadIdx.x & 63) == 0) ws[threadIdx.x >> 6] = v;
  __syncthreads();
  if (threadIdx.x == 0) bsum[blockIdx.x] = ws[0] + ws[1] + ws[2] + ws[3];
}

// scan the 196 block sums; also zero SUMS/CNT with idle threads
__global__ __launch_bounds__(256) void scanB_kernel(
    int* __restrict__ bsum, int* __restrict__ row_ptr,
    float* __restrict__ sums_zero, int nz) {
  __shared__ int sh[256];
  const int t = threadIdx.x;
  int v = (t < SCAN_BLOCKS) ? bsum[t] : 0;
  sh[t] = v;
  __syncthreads();
  for (int o = 1; o < 256; o <<= 1) {
    const int u = (t >= o) ? sh[t - o] : 0;
    __syncthreads();
    sh[t] += u;
    __syncthreads();
  }
  bsum[t] = (t == 0) ? 0 : sh[t - 1];   // exclusive
  if (t == 0) row_ptr[N_NODES] = N_EDGES;
  for (int i = t; i < nz; i += 256) sums_zero[i] = 0.f;
}

__global__ __launch_bounds__(256) void scanC_kernel(
    const int* __restrict__ deg, const int* __restrict__ bsum,
    int* __restrict__ row_ptr, int* __restrict__ cursor) {
  __shared__ int sh[256];
  const int t = threadIdx.x;
  const int i = blockIdx.x * 256 + t;
  const int v = (i < N_NODES) ? deg[i] : 0;
  sh[t] = v;
  __syncthreads();
  for (int o = 1; o < 256; o <<= 1) {
    const int u = (t >= o) ? sh[t - o] : 0;
    __syncthreads();
    sh[t] += u;
    __syncthreads();
  }
  if (i < N_NODES) {
    const int excl = bsum[blockIdx.x] + sh[t] - v;
    row_ptr[i] = excl;
    cursor[i] = excl;
  }
}

__global__ __launch_bounds__(256) void fill_kernel(
    const int* __restrict__ src, const int* __restrict__ dst,
    int* __restrict__ cursor, int* __restrict__ adj) {
  const int e = blockIdx.x * 256 + threadIdx.x;
  if (e < N_EDGES) {
    const int pos = atomicAdd(&cursor[dst[e]], 1);
    adj[pos] = src[e];
  }
}

// ---------------------------------------------------------------------------
// gather + fused update, float4, unroll-2: 8 lanes/node, lane owns 4 feats.
// H[n] = leaky(H[n] + sum_{k in row(n)} T[adj[k]])
// ---------------------------------------------------------------------------
__global__ __launch_bounds__(256) void gather_update_v3(
    const float* __restrict__ T, const int* __restrict__ row_ptr,
    const int* __restrict__ adj, float* __restrict__ H) {
  const int gid = blockIdx.x * 256 + threadIdx.x;
  const int n = gid >> 3;
  const int q = gid & 7;
  if (n >= N_NODES) return;
  const int lo = row_ptr[n], hi = row_ptr[n + 1];
  const float4* __restrict__ T4 = reinterpret_cast<const float4*>(T);
  float4 acc = make_float4(0.f, 0.f, 0.f, 0.f);
  int k = lo;
  for (; k + 1 < hi; k += 2) {
    const int s0 = adj[k];
    const int s1 = adj[k + 1];
    const float4 t0 = T4[s0 * 8 + q];
    const float4 t1 = T4[s1 * 8 + q];
    acc.x += t0.x + t1.x; acc.y += t0.y + t1.y;
    acc.z += t0.z + t1.z; acc.w += t0.w + t1.w;
  }
  if (k < hi) {
    const float4 t = T4[adj[k] * 8 + q];
    acc.x += t.x; acc.y += t.y; acc.z += t.z; acc.w += t.w;
  }
  float4* __restrict__ H4 = reinterpret_cast<float4*>(H);
  float4 h = H4[n * 8 + q];
  h.x += acc.x; h.y += acc.y; h.z += acc.z; h.w += acc.w;
  h.x = (h.x >= 0.f) ? h.x : NEG_SLOPE * h.x;
  h.y = (h.y >= 0.f) ? h.y : NEG_SLOPE * h.y;
  h.z = (h.z >= 0.f) ? h.z : NEG_SLOPE * h.z;
  h.w = (h.w >= 0.f) ? h.w : NEG_SLOPE * h.w;
  H4[n * 8 + q] = h;
}

// ---------------------------------------------------------------------------
// Input KAN v13: 256 thr, 128 nodes/block; thread = (oq 0..7, grp 0..31).
// LDS holds ONLY trig (c1,s1) for all 64 i (stride 257: <=2-way conflicts)
// -> exactly 2 barriers per kernel (v9 had 16). Weights read from GLOBAL
// with direct-indexed float4 loads (8-lane-shared lines, L1/L2 broadcast;
// immediate offsets fit 13-bit). 64KB weight set is L2-resident.
// Fallback: if FETCH balloons (spills), revert to v9 (proven 59-60us).
// ---------------------------------------------------------------------------
__global__ __launch_bounds__(256, 2) void kan_input_v13(
    const float* __restrict__ X, const float* __restrict__ W,
    float* __restrict__ H) {
  extern __shared__ float tg[];            // 64 * 257 floats = 65.8KB
  const int tid = threadIdx.x;
  const int n0 = blockIdx.x * 128;

  // phase 1: (c1,s1) for 128 nodes x 64 i.
  // thread's i = tid&63 fixed; nodes p*4 + (tid>>6). Wave reads one
  // contiguous 256B X row per p; writes <=2-way banked.
  {
    const int i = tid & 63;
    const int w = tid >> 6;
#pragma unroll
    for (int p = 0; p < 32; ++p) {
      const int node = p * 4 + w;
      const int gn = n0 + node;
      const int gs = (gn < N_NODES) ? gn : (N_NODES - 1);
      const float v = X[gs * IN_FEAT + i];
      float s1, c1;
      sincosf(v, &s1, &c1);
      *reinterpret_cast<float2*>(&tg[i * 257 + node * 2]) = make_float2(c1, s1);
    }
  }
  __syncthreads();

  const int oq = tid & 7;        // outputs 4*oq .. 4*oq+3
  const int grp = tid >> 3;      // 0..31 -> local nodes 4*grp .. 4*grp+3
  const int nb = 4 * grp;

  // global weight bases for this oq (cos / sin planes)
  const float4* __restrict__ Wg = reinterpret_cast<const float4*>(W);
  const float4* __restrict__ WC = Wg + (4 * oq) * 64;          // + q*64 + i
  const float4* __restrict__ WS = Wg + 2048 + (4 * oq) * 64;

  float acc[4][4];
#pragma unroll
  for (int n = 0; n < 4; ++n)
#pragma unroll
    for (int q = 0; q < 4; ++q) acc[n][q] = 0.f;

#pragma unroll 4
  for (int i = 0; i < IN_FEAT; ++i) {
    const float4 tA = *reinterpret_cast<const float4*>(&tg[i * 257 + nb * 2]);
    const float4 tB = *reinterpret_cast<const float4*>(&tg[i * 257 + nb * 2 + 4]);
    const float bc[4] = {tA.x, tA.z, tB.x, tB.z};
    const float bs[4] = {tA.y, tA.w, tB.y, tB.w};
    float cN[4][4], sN[4][4];
#pragma unroll
    for (int n = 0; n < 4; ++n) {
      const float c1 = bc[n], s1 = bs[n];
      const float c2 = c1*c1 - s1*s1, s2 = s1*c1 + c1*s1;
      const float c3 = c2*c1 - s2*s1, s3 = s2*c1 + c2*s1;
      const float c4 = c3*c1 - s3*s1, s4 = s3*c1 + c3*s1;
      cN[n][0]=c1; cN[n][1]=c2; cN[n][2]=c3; cN[n][3]=c4;
      sN[n][0]=s1; sN[n][1]=s2; sN[n][2]=s3; sN[n][3]=s4;
    }
#pragma unroll
    for (int q = 0; q < 4; ++q) {
      const float4 a = WC[q * 64 + i];
      const float4 b = WS[q * 64 + i];
#pragma unroll
      for (int n = 0; n < 4; ++n)
        acc[n][q] += cN[n][0]*a.x + cN[n][1]*a.y + cN[n][2]*a.z + cN[n][3]*a.w
                   + sN[n][0]*b.x + sN[n][1]*b.y + sN[n][2]*b.z + sN[n][3]*b.w;
    }
  }
#pragma unroll
  for (int n = 0; n < 4; ++n) {
    const int gn = n0 + nb + n;
    if (gn < N_NODES)
      *reinterpret_cast<float4*>(&H[gn * HIDDEN + 4 * oq]) =
          make_float4(acc[n][0], acc[n][1], acc[n][2], acc[n][3]);
  }
}

// ---------------------------------------------------------------------------
// Conv KAN v13: same zero-weight-LDS structure, 32 i. Trig 32.9KB -> can run
// 3 blocks/CU. Weight offsets (q*32+i)*16B <= 2032 fit immediates.
// ---------------------------------------------------------------------------
__global__ __launch_bounds__(256, 3) void kan_node_v13(
    const float* __restrict__ Hin, const float* __restrict__ W,
    float* __restrict__ T) {
  extern __shared__ float tg[];            // 32 * 257 floats = 32.9KB
  const int tid = threadIdx.x;
  const int n0 = blockIdx.x * 128;

  // phase 1: (c1,s1) for 128 nodes x 32 i. i = tid&31; node = p*8 + tid>>5.
  {
    const int i = tid & 31;
    const int hw = tid >> 5;     // 0..7
#pragma unroll
    for (int p = 0; p < 16; ++p) {
      const int node = p * 8 + hw;
      const int gn = n0 + node;
      const int gs = (gn < N_NODES) ? gn : (N_NODES - 1);
      const float v = Hin[gs * HIDDEN + i];
      float s1, c1;
      sincosf(v, &s1, &c1);
      *reinterpret_cast<float2*>(&tg[i * 257 + node * 2]) = make_float2(c1, s1);
    }
  }
  __syncthreads();

  const int oq = tid & 7;
  const int grp = tid >> 3;
  const int nb = 4 * grp;

  const float4* __restrict__ Wg = reinterpret_cast<const float4*>(W);
  const float4* __restrict__ WC = Wg + (4 * oq) * 32;          // + q*32 + i
  const float4* __restrict__ WS = Wg + 1024 + (4 * oq) * 32;

  float acc[4][4];
#pragma unroll
  for (int n = 0; n < 4; ++n)
#pragma unroll
    for (int q = 0; q < 4; ++q) acc[n][q] = 0.f;

#pragma unroll 4
  for (int i = 0; i < HIDDEN; ++i) {
    const float4 tA = *reinterpret_cast<const float4*>(&tg[i * 257 + nb * 2]);
    const float4 tB = *reinterpret_cast<const float4*>(&tg[i * 257 + nb * 2 + 4]);
    const float bc[4] = {tA.x, tA.z, tB.x, tB.z};
    const float bs[4] = {tA.y, tA.w, tB.y, tB.w};
    float cN[4][4], sN[4][4];
#pragma unroll
    for (int n = 0; n < 4; ++n) {
      const float c1 = bc[n], s1 = bs[n];
      const float c2 = c1*c1 - s1*s1, s2 = s1*c1 + c1*s1;
      const float c3 = c2*c1 - s2*s1, s3 = s2*c1 + c2*s1;
      const float c4 = c3*c1 - s3*s1, s4 = s3*c1 + c3*s1;
      cN[n][0]=c1; cN[n][1]=c2; cN[n][2]=c3; cN[n][3]=c4;
      sN[n][0]=s1; sN[n][1]=s2; sN[n][2]=s3; sN[n][3]=s4;
    }
#pragma unroll
    for (int q = 0; q < 4; ++q) {
      const float4 a = WC[q * 32 + i];
      const float4 b = WS[q * 32 + i];
#pragma unroll
      for (int n = 0; n < 4; ++n)
        acc[n][q] += cN[n][0]*a.x + cN[n][1]*a.y + cN[n][2]*a.z + cN[n][3]*a.w
                   + sN[n][0]*b.x + sN[n][1]*b.y + sN[n][2]*b.z + sN[n][3]*b.w;
    }
  }
#pragma unroll
  for (int n = 0; n < 4; ++n) {
    const int gn = n0 + nb + n;
    if (gn < N_NODES)
      *reinterpret_cast<float4*>(&T[gn * HIDDEN + 4 * oq]) =
          make_float4(acc[n][0], acc[n][1], acc[n][2], acc[n][3]);
  }
}

// ---------------------------------------------------------------------------
// pool via run-length over sorted batch
// ---------------------------------------------------------------------------
#define POOL_RANGES 2048
__global__ __launch_bounds__(256) void pool_rl(
    const float* __restrict__ H, const int* __restrict__ batch,
    float* __restrict__ sums, float* __restrict__ cnt) {
  const int tid = threadIdx.x;
  const int f = tid & 31;
  const int r = blockIdx.x * 8 + (tid >> 5);
  const int PER = (N_NODES + POOL_RANGES - 1) / POOL_RANGES;  // 25
  int n = r * PER;
  const int end = (n + PER < N_NODES) ? n + PER : N_NODES;
  if (n >= end) return;
  int g = batch[n];
  float acc = 0.f, c = 0.f;
  for (; n < end; ++n) {
    const int gn = batch[n];
    if (gn != g) {
      atomicAdd(&sums[g * HIDDEN + f], acc);
      if (f == 0) atomicAdd(&cnt[g], c);
      g = gn; acc = 0.f; c = 0.f;
    }
    acc += H[n * HIDDEN + f];
    c += 1.f;
  }
  atomicAdd(&sums[g * HIDDEN + f], acc);
  if (f == 0) atomicAdd(&cnt[g], c);
}

// ---------------------------------------------------------------------------
__global__ __launch_bounds__(128) void readout_kernel(
    const float* __restrict__ sums, const float* __restrict__ cnt,
    const float* __restrict__ Wout, const float* __restrict__ bout,
    float* __restrict__ out) {
  const int g = threadIdx.x;
  if (g < N_GRAPHS) {
    const float c = fmaxf(cnt[g], 1.0f);
    float z = 0.f;
#pragma unroll
    for (int i = 0; i < HIDDEN; ++i) {
      const float y = sums[g * HIDDEN + i] / c;
      z += cosf(y) * Wout[i] + sinf(y) * Wout[HIDDEN + i];
    }
    z += bout[0];
    out[g] = 1.0f / (1.0f + expf(-z));
  }
}

// ---------------------------------------------------------------------------
extern "C" void kernel_launch(void* const* d_in, const int* in_sizes, int n_in,
                              void* d_out, int out_size, void* d_ws, size_t ws_size,
                              hipStream_t stream) {
  const float* x        = (const float*)d_in[0];
  const int*   eidx     = (const int*)d_in[1];
  const int*   batch    = (const int*)d_in[2];
  const float* W_in     = (const float*)d_in[3];
  const float* W_conv   = (const float*)d_in[4];
  const float* W_out    = (const float*)d_in[5];
  const float* b_out    = (const float*)d_in[6];
  float* out            = (float*)d_out;

  const int* src = eidx;            // edge_index[0]
  const int* dst = eidx + N_EDGES;  // edge_index[1]

  float* ws = (float*)d_ws;
  float* H       = ws;                         // 1.6M floats
  float* T       = ws + NH;                    // 1.6M floats
  int*   row_ptr = (int*)(ws + 2 * NH);        // 50001 (pad 50008)
  int*   deg     = row_ptr + 50008;            // 50000 (pad 50048)
  int*   cursor  = deg + 50048;                // 50000 (pad 50048)
  int*   bsum    = cursor + 50048;             // 256
  int*   adj     = bsum + 256;                 // 800000
  float* SUMS    = (float*)(adj + 800000);     // 4096
  float* CNT     = SUMS + 4096;                // 128

  const int kan_blocks  = (N_NODES + 127) / 128;     // 391
  const int edge_blocks = (N_EDGES + 255) / 256;     // 3125
  const int gath_blocks = (N_NODES * 8 + 255) / 256; // 1563

  const size_t in_lds   = (size_t)(64 * 257) * 4;    // 65792 B (2 blocks/CU)
  const size_t conv_lds = (size_t)(32 * 257) * 4;    // 32896 B (3 blocks/CU)
  const int WCONV_STRIDE = 2 * HIDDEN * HIDDEN * GRID_SZ;  // 8192

  // --- CSR build (multi-block scan; every kernel chip-wide)
  zero_int_kernel<<<SCAN_BLOCKS, 256, 0, stream>>>(deg, N_NODES);
  hist_kernel<<<edge_blocks, 256, 0, stream>>>(dst, deg);
  scanA_kernel<<<SCAN_BLOCKS, 256, 0, stream>>>(deg, bsum);
  scanB_kernel<<<1, 256, 0, stream>>>(bsum, row_ptr, SUMS, N_GRAPHS * HIDDEN + N_GRAPHS);
  scanC_kernel<<<SCAN_BLOCKS, 256, 0, stream>>>(deg, bsum, row_ptr, cursor);
  fill_kernel<<<edge_blocks, 256, 0, stream>>>(src, dst, cursor, adj);

  // --- input KAN projection: H = KAN_in(x)
  kan_input_v13<<<kan_blocks, 256, in_lds, stream>>>(x, W_in, H);

  // --- layer 0: T = KAN_0(H); H = leaky(H + gather(T))
  kan_node_v13<<<kan_blocks, 256, conv_lds, stream>>>(H, W_conv, T);
  gather_update_v3<<<gath_blocks, 256, 0, stream>>>(T, row_ptr, adj, H);

  // --- layer 1
  kan_node_v13<<<kan_blocks, 256, conv_lds, stream>>>(H, W_conv + WCONV_STRIDE, T);
  gather_update_v3<<<gath_blocks, 256, 0, stream>>>(T, row_ptr, adj, H);

  // --- pool + readout
  pool_rl<<<POOL_RANGES / 8, 256, 0, stream>>>(H, batch, SUMS, CNT);
  readout_kernel<<<1, 128, 0, stream>>>(SUMS, CNT, W_out, b_out, out);
}

// Round 19
// 340.971 us; speedup vs baseline: 1.4239x; 1.4239x over previous
//
#include <hip/hip_runtime.h>
#include <math.h>

#define N_NODES   50000
#define N_EDGES   800000
#define IN_FEAT   64
#define HIDDEN    32
#define GRID_SZ   4
#define N_GRAPHS  128
#define NEG_SLOPE 0.01f
#define SCAN_BLOCKS 196   // ceil(50000/256)
#define NH (N_NODES * HIDDEN)   // 1.6M

// ---------------------------------------------------------------------------
__global__ __launch_bounds__(256) void zero_int_kernel(int* __restrict__ p, int n) {
  const int i = blockIdx.x * 256 + threadIdx.x;
  if (i < n) p[i] = 0;
}

// ---------------------------------------------------------------------------
// CSR build
// ---------------------------------------------------------------------------
__global__ __launch_bounds__(256) void hist_kernel(
    const int* __restrict__ dst, int* __restrict__ deg) {
  const int e = blockIdx.x * 256 + threadIdx.x;
  if (e < N_EDGES) atomicAdd(&deg[dst[e]], 1);
}

__global__ __launch_bounds__(256) void scanA_kernel(
    const int* __restrict__ deg, int* __restrict__ bsum) {
  const int i = blockIdx.x * 256 + threadIdx.x;
  int v = (i < N_NODES) ? deg[i] : 0;
#pragma unroll
  for (int o = 32; o > 0; o >>= 1) v += __shfl_down(v, o, 64);
  __shared__ int ws[4];
  if ((threadIdx.x & 63) == 0) ws[threadIdx.x >> 6] = v;
  __syncthreads();
  if (threadIdx.x == 0) bsum[blockIdx.x] = ws[0] + ws[1] + ws[2] + ws[3];
}

// scan the 196 block sums; also zero SUMS/CNT with idle threads
__global__ __launch_bounds__(256) void scanB_kernel(
    int* __restrict__ bsum, int* __restrict__ row_ptr,
    float* __restrict__ sums_zero, int nz) {
  __shared__ int sh[256];
  const int t = threadIdx.x;
  int v = (t < SCAN_BLOCKS) ? bsum[t] : 0;
  sh[t] = v;
  __syncthreads();
  for (int o = 1; o < 256; o <<= 1) {
    const int u = (t >= o) ? sh[t - o] : 0;
    __syncthreads();
    sh[t] += u;
    __syncthreads();
  }
  bsum[t] = (t == 0) ? 0 : sh[t - 1];   // exclusive
  if (t == 0) row_ptr[N_NODES] = N_EDGES;
  for (int i = t; i < nz; i += 256) sums_zero[i] = 0.f;
}

__global__ __launch_bounds__(256) void scanC_kernel(
    const int* __restrict__ deg, const int* __restrict__ bsum,
    int* __restrict__ row_ptr, int* __restrict__ cursor) {
  __shared__ int sh[256];
  const int t = threadIdx.x;
  const int i = blockIdx.x * 256 + t;
  const int v = (i < N_NODES) ? deg[i] : 0;
  sh[t] = v;
  __syncthreads();
  for (int o = 1; o < 256; o <<= 1) {
    const int u = (t >= o) ? sh[t - o] : 0;
    __syncthreads();
    sh[t] += u;
    __syncthreads();
  }
  if (i < N_NODES) {
    const int excl = bsum[blockIdx.x] + sh[t] - v;
    row_ptr[i] = excl;
    cursor[i] = excl;
  }
}

__global__ __launch_bounds__(256) void fill_kernel(
    const int* __restrict__ src, const int* __restrict__ dst,
    int* __restrict__ cursor, int* __restrict__ adj) {
  const int e = blockIdx.x * 256 + threadIdx.x;
  if (e < N_EDGES) {
    const int pos = atomicAdd(&cursor[dst[e]], 1);
    adj[pos] = src[e];
  }
}

// ---------------------------------------------------------------------------
// gather + fused update, float4, unroll-2: 8 lanes/node, lane owns 4 feats.
// H[n] = leaky(H[n] + sum_{k in row(n)} T[adj[k]])
// ---------------------------------------------------------------------------
__global__ __launch_bounds__(256) void gather_update_v3(
    const float* __restrict__ T, const int* __restrict__ row_ptr,
    const int* __restrict__ adj, float* __restrict__ H) {
  const int gid = blockIdx.x * 256 + threadIdx.x;
  const int n = gid >> 3;
  const int q = gid & 7;
  if (n >= N_NODES) return;
  const int lo = row_ptr[n], hi = row_ptr[n + 1];
  const float4* __restrict__ T4 = reinterpret_cast<const float4*>(T);
  float4 acc = make_float4(0.f, 0.f, 0.f, 0.f);
  int k = lo;
  for (; k + 1 < hi; k += 2) {
    const int s0 = adj[k];
    const int s1 = adj[k + 1];
    const float4 t0 = T4[s0 * 8 + q];
    const float4 t1 = T4[s1 * 8 + q];
    acc.x += t0.x + t1.x; acc.y += t0.y + t1.y;
    acc.z += t0.z + t1.z; acc.w += t0.w + t1.w;
  }
  if (k < hi) {
    const float4 t = T4[adj[k] * 8 + q];
    acc.x += t.x; acc.y += t.y; acc.z += t.z; acc.w += t.w;
  }
  float4* __restrict__ H4 = reinterpret_cast<float4*>(H);
  float4 h = H4[n * 8 + q];
  h.x += acc.x; h.y += acc.y; h.z += acc.z; h.w += acc.w;
  h.x = (h.x >= 0.f) ? h.x : NEG_SLOPE * h.x;
  h.y = (h.y >= 0.f) ? h.y : NEG_SLOPE * h.y;
  h.z = (h.z >= 0.f) ? h.z : NEG_SLOPE * h.z;
  h.w = (h.w >= 0.f) ? h.w : NEG_SLOPE * h.w;
  H4[n * 8 + q] = h;
}

// ---------------------------------------------------------------------------
// Input KAN v14b = v9 inner loop + 16-i chunks (8 barriers vs v9's 16).
// FIX vs round 18: ch < 4 (4 chunks x 16 i = all 64 features; r18 had 2).
// LDS exactly 80KB: 64KB swizzled weights + 16KB trig (stride 256, node
// XOR-swizzled by ((il&3)<<2); mask in node bits 2-3 so 4-node float4
// reads stay contiguous and position enb+j holds node nb+j).
// Phase-2 FMA loop is byte-identical to v9 (proven no-spill @ VGPR 116).
// ---------------------------------------------------------------------------
__global__ __launch_bounds__(256, 2) void kan_input_v14(
    const float* __restrict__ X, const float* __restrict__ W,
    float* __restrict__ H) {
  extern __shared__ float smem[];
  float4* __restrict__ w4 = reinterpret_cast<float4*>(smem);   // 4096 f4
  float* __restrict__ tg = smem + 16384;                       // 16*256 floats
  const int tid = threadIdx.x;
  const int n0 = blockIdx.x * 128;

  // stage weights, swizzled: slot-in-row = i ^ ((o>>2)&7)   (v9 layout)
  const float4* __restrict__ Wg = reinterpret_cast<const float4*>(W);
#pragma unroll
  for (int r = 0; r < 16; ++r) {
    const int idx = r * 256 + tid;       // 0..4095
    const int part = idx >> 11;
    const int rem = idx & 2047;
    const int o = rem >> 6;
    const int i = rem & 63;
    w4[part * 2048 + o * 64 + (i ^ ((o >> 2) & 7))] = Wg[idx];
  }

  const int oq = tid & 7;        // outputs 4*oq .. 4*oq+3
  const int grp = tid >> 3;      // 0..31 -> local nodes 4*grp .. 4*grp+3
  const int nb = 4 * grp;

  float acc[4][4];
#pragma unroll
  for (int n = 0; n < 4; ++n)
#pragma unroll
    for (int q = 0; q < 4; ++q) acc[n][q] = 0.f;

  for (int ch = 0; ch < 4; ++ch) {       // 4 chunks of 16 i = 64 feats
    __syncthreads();   // protect tg (prev chunk readers) + weight staging
    // phase 1: (c1,s1) for 128 nodes x 16 i; node slot XOR-swizzled
    {
      const int il = tid & 15;
      const int w = tid >> 4;            // 0..15
      const int msk = (il & 3) << 2;     // bits 2-3
#pragma unroll
      for (int p = 0; p < 8; ++p) {
        const int node = p * 16 + w;
        const int gn = n0 + node;
        const int gs = (gn < N_NODES) ? gn : (N_NODES - 1);
        const float v = X[gs * IN_FEAT + ch * 16 + il];
        float s1, c1;
        sincosf(v, &s1, &c1);
        const int en = node ^ msk;
        *reinterpret_cast<float2*>(&tg[il * 256 + en * 2]) = make_float2(c1, s1);
      }
    }
    __syncthreads();
    // phase 2 (identical math to v9)
#pragma unroll
    for (int il = 0; il < 16; ++il) {
      const int i = ch * 16 + il;
      const int enb = nb ^ ((il & 3) << 2);
      const float4 tA = *reinterpret_cast<const float4*>(&tg[il * 256 + enb * 2]);
      const float4 tB = *reinterpret_cast<const float4*>(&tg[il * 256 + enb * 2 + 4]);
      const float bc[4] = {tA.x, tA.z, tB.x, tB.z};
      const float bs[4] = {tA.y, tA.w, tB.y, tB.w};
      float cN[4][4], sN[4][4];
#pragma unroll
      for (int n = 0; n < 4; ++n) {
        const float c1 = bc[n], s1 = bs[n];
        const float c2 = c1*c1 - s1*s1, s2 = s1*c1 + c1*s1;
        const float c3 = c2*c1 - s2*s1, s3 = s2*c1 + c2*s1;
        const float c4 = c3*c1 - s3*s1, s4 = s3*c1 + c3*s1;
        cN[n][0]=c1; cN[n][1]=c2; cN[n][2]=c3; cN[n][3]=c4;
        sN[n][0]=s1; sN[n][1]=s2; sN[n][2]=s3; sN[n][3]=s4;
      }
      const int sl = i ^ oq;
#pragma unroll
      for (int q = 0; q < 4; ++q) {
        const float4 a = w4[(4 * oq + q) * 64 + sl];
        const float4 b = w4[2048 + (4 * oq + q) * 64 + sl];
#pragma unroll
        for (int n = 0; n < 4; ++n)
          acc[n][q] += cN[n][0]*a.x + cN[n][1]*a.y + cN[n][2]*a.z + cN[n][3]*a.w
                     + sN[n][0]*b.x + sN[n][1]*b.y + sN[n][2]*b.z + sN[n][3]*b.w;
      }
    }
  }
#pragma unroll
  for (int n = 0; n < 4; ++n) {
    const int gn = n0 + nb + n;
    if (gn < N_NODES)
      *reinterpret_cast<float4*>(&H[gn * HIDDEN + 4 * oq]) =
          make_float4(acc[n][0], acc[n][1], acc[n][2], acc[n][3]);
  }
}

// ---------------------------------------------------------------------------
// Conv KAN v9 (PROVEN @ rounds 12/16): 2 barriers already. DO NOT MODIFY.
// ---------------------------------------------------------------------------
__global__ __launch_bounds__(256, 2) void kan_node_v9(
    const float* __restrict__ Hin, const float* __restrict__ W,
    float* __restrict__ T) {
  extern __shared__ float smem[];
  float4* __restrict__ w4 = reinterpret_cast<float4*>(smem);   // 2048 f4
  float* __restrict__ tg = smem + 8192;                        // 32*260 floats
  const int tid = threadIdx.x;
  const int n0 = blockIdx.x * 128;

  const float4* __restrict__ Wg = reinterpret_cast<const float4*>(W);
#pragma unroll
  for (int r = 0; r < 8; ++r) {
    const int idx = r * 256 + tid;       // 0..2047
    const int part = idx >> 10;
    const int rem = idx & 1023;
    const int o = rem >> 5;
    const int i = rem & 31;
    w4[part * 1024 + o * 32 + (i ^ ((o >> 2) & 7))] = Wg[idx];
  }

  // phase 1: (c1,s1) for 128 nodes x 32 i
#pragma unroll
  for (int p = 0; p < 16; ++p) {
    const int lin = p * 256 + tid;
    const int il = lin & 31;
    const int node = lin >> 5;       // 0..127
    const int gn = n0 + node;
    const int gs = (gn < N_NODES) ? gn : (N_NODES - 1);
    const float v = Hin[gs * HIDDEN + il];
    float s1, c1;
    sincosf(v, &s1, &c1);
    *reinterpret_cast<float2*>(&tg[il * 260 + node * 2]) = make_float2(c1, s1);
  }
  __syncthreads();

  const int oq = tid & 7;
  const int grp = tid >> 3;
  const int nb = 4 * grp;

  float acc[4][4];
#pragma unroll
  for (int n = 0; n < 4; ++n)
#pragma unroll
    for (int q = 0; q < 4; ++q) acc[n][q] = 0.f;

#pragma unroll 4
  for (int i = 0; i < HIDDEN; ++i) {
    const float4 tA = *reinterpret_cast<const float4*>(&tg[i * 260 + nb * 2]);
    const float4 tB = *reinterpret_cast<const float4*>(&tg[i * 260 + nb * 2 + 4]);
    const float bc[4] = {tA.x, tA.z, tB.x, tB.z};
    const float bs[4] = {tA.y, tA.w, tB.y, tB.w};
    float cN[4][4], sN[4][4];
#pragma unroll
    for (int n = 0; n < 4; ++n) {
      const float c1 = bc[n], s1 = bs[n];
      const float c2 = c1*c1 - s1*s1, s2 = s1*c1 + c1*s1;
      const float c3 = c2*c1 - s2*s1, s3 = s2*c1 + c2*s1;
      const float c4 = c3*c1 - s3*s1, s4 = s3*c1 + c3*s1;
      cN[n][0]=c1; cN[n][1]=c2; cN[n][2]=c3; cN[n][3]=c4;
      sN[n][0]=s1; sN[n][1]=s2; sN[n][2]=s3; sN[n][3]=s4;
    }
    const int sl = i ^ oq;
#pragma unroll
    for (int q = 0; q < 4; ++q) {
      const float4 a = w4[(4 * oq + q) * 32 + sl];
      const float4 b = w4[1024 + (4 * oq + q) * 32 + sl];
#pragma unroll
      for (int n = 0; n < 4; ++n)
        acc[n][q] += cN[n][0]*a.x + cN[n][1]*a.y + cN[n][2]*a.z + cN[n][3]*a.w
                   + sN[n][0]*b.x + sN[n][1]*b.y + sN[n][2]*b.z + sN[n][3]*b.w;
    }
  }
#pragma unroll
  for (int n = 0; n < 4; ++n) {
    const int gn = n0 + nb + n;
    if (gn < N_NODES)
      *reinterpret_cast<float4*>(&T[gn * HIDDEN + 4 * oq]) =
          make_float4(acc[n][0], acc[n][1], acc[n][2], acc[n][3]);
  }
}

// ---------------------------------------------------------------------------
// pool via run-length over sorted batch
// ---------------------------------------------------------------------------
#define POOL_RANGES 2048
__global__ __launch_bounds__(256) void pool_rl(
    const float* __restrict__ H, const int* __restrict__ batch,
    float* __restrict__ sums, float* __restrict__ cnt) {
  const int tid = threadIdx.x;
  const int f = tid & 31;
  const int r = blockIdx.x * 8 + (tid >> 5);
  const int PER = (N_NODES + POOL_RANGES - 1) / POOL_RANGES;  // 25
  int n = r * PER;
  const int end = (n + PER < N_NODES) ? n + PER : N_NODES;
  if (n >= end) return;
  int g = batch[n];
  float acc = 0.f, c = 0.f;
  for (; n < end; ++n) {
    const int gn = batch[n];
    if (gn != g) {
      atomicAdd(&sums[g * HIDDEN + f], acc);
      if (f == 0) atomicAdd(&cnt[g], c);
      g = gn; acc = 0.f; c = 0.f;
    }
    acc += H[n * HIDDEN + f];
    c += 1.f;
  }
  atomicAdd(&sums[g * HIDDEN + f], acc);
  if (f == 0) atomicAdd(&cnt[g], c);
}

// ---------------------------------------------------------------------------
__global__ __launch_bounds__(128) void readout_kernel(
    const float* __restrict__ sums, const float* __restrict__ cnt,
    const float* __restrict__ Wout, const float* __restrict__ bout,
    float* __restrict__ out) {
  const int g = threadIdx.x;
  if (g < N_GRAPHS) {
    const float c = fmaxf(cnt[g], 1.0f);
    float z = 0.f;
#pragma unroll
    for (int i = 0; i < HIDDEN; ++i) {
      const float y = sums[g * HIDDEN + i] / c;
      z += cosf(y) * Wout[i] + sinf(y) * Wout[HIDDEN + i];
    }
    z += bout[0];
    out[g] = 1.0f / (1.0f + expf(-z));
  }
}

// ---------------------------------------------------------------------------
extern "C" void kernel_launch(void* const* d_in, const int* in_sizes, int n_in,
                              void* d_out, int out_size, void* d_ws, size_t ws_size,
                              hipStream_t stream) {
  const float* x        = (const float*)d_in[0];
  const int*   eidx     = (const int*)d_in[1];
  const int*   batch    = (const int*)d_in[2];
  const float* W_in     = (const float*)d_in[3];
  const float* W_conv   = (const float*)d_in[4];
  const float* W_out    = (const float*)d_in[5];
  const float* b_out    = (const float*)d_in[6];
  float* out            = (float*)d_out;

  const int* src = eidx;            // edge_index[0]
  const int* dst = eidx + N_EDGES;  // edge_index[1]

  float* ws = (float*)d_ws;
  float* H       = ws;                         // 1.6M floats
  float* T       = ws + NH;                    // 1.6M floats
  int*   row_ptr = (int*)(ws + 2 * NH);        // 50001 (pad 50008)
  int*   deg     = row_ptr + 50008;            // 50000 (pad 50048)
  int*   cursor  = deg + 50048;                // 50000 (pad 50048)
  int*   bsum    = cursor + 50048;             // 256
  int*   adj     = bsum + 256;                 // 800000
  float* SUMS    = (float*)(adj + 800000);     // 4096
  float* CNT     = SUMS + 4096;                // 128

  const int kan_blocks  = (N_NODES + 127) / 128;     // 391
  const int edge_blocks = (N_EDGES + 255) / 256;     // 3125
  const int gath_blocks = (N_NODES * 8 + 255) / 256; // 1563

  const size_t in_lds   = (size_t)(16384 + 16 * 256) * 4;  // 81920 B (2/CU)
  const size_t conv_lds = (size_t)(8192 + 32 * 260) * 4;   // 66048 B (2/CU)
  const int WCONV_STRIDE = 2 * HIDDEN * HIDDEN * GRID_SZ;  // 8192

  // --- CSR build (multi-block scan; every kernel chip-wide)
  zero_int_kernel<<<SCAN_BLOCKS, 256, 0, stream>>>(deg, N_NODES);
  hist_kernel<<<edge_blocks, 256, 0, stream>>>(dst, deg);
  scanA_kernel<<<SCAN_BLOCKS, 256, 0, stream>>>(deg, bsum);
  scanB_kernel<<<1, 256, 0, stream>>>(bsum, row_ptr, SUMS, N_GRAPHS * HIDDEN + N_GRAPHS);
  scanC_kernel<<<SCAN_BLOCKS, 256, 0, stream>>>(deg, bsum, row_ptr, cursor);
  fill_kernel<<<edge_blocks, 256, 0, stream>>>(src, dst, cursor, adj);

  // --- input KAN projection: H = KAN_in(x)
  kan_input_v14<<<kan_blocks, 256, in_lds, stream>>>(x, W_in, H);

  // --- layer 0: T = KAN_0(H); H = leaky(H + gather(T))
  kan_node_v9<<<kan_blocks, 256, conv_lds, stream>>>(H, W_conv, T);
  gather_update_v3<<<gath_blocks, 256, 0, stream>>>(T, row_ptr, adj, H);

  // --- layer 1
  kan_node_v9<<<kan_blocks, 256, conv_lds, stream>>>(H, W_conv + WCONV_STRIDE, T);
  gather_update_v3<<<gath_blocks, 256, 0, stream>>>(T, row_ptr, adj, H);

  // --- pool + readout
  pool_rl<<<POOL_RANGES / 8, 256, 0, stream>>>(H, batch, SUMS, CNT);
  readout_kernel<<<1, 128, 0, stream>>>(SUMS, CNT, W_out, b_out, out);
}

// Round 20
// 275.803 us; speedup vs baseline: 1.7604x; 1.2363x over previous
//
#include <hip/hip_runtime.h>
#include <math.h>

#define N_NODES   50000
#define N_EDGES   800000
#define IN_FEAT   64
#define HIDDEN    32
#define GRID_SZ   4
#define N_GRAPHS  128
#define NEG_SLOPE 0.01f
#define SCAN_BLOCKS 196   // ceil(50000/256)
#define NH (N_NODES * HIDDEN)   // 1.6M

// ---------------------------------------------------------------------------
__global__ __launch_bounds__(256) void zero_int_kernel(int* __restrict__ p, int n) {
  const int i = blockIdx.x * 256 + threadIdx.x;
  if (i < n) p[i] = 0;
}

// ---------------------------------------------------------------------------
// CSR build
// ---------------------------------------------------------------------------
__global__ __launch_bounds__(256) void hist_kernel(
    const int* __restrict__ dst, int* __restrict__ deg) {
  const int e = blockIdx.x * 256 + threadIdx.x;
  if (e < N_EDGES) atomicAdd(&deg[dst[e]], 1);
}

__global__ __launch_bounds__(256) void scanA_kernel(
    const int* __restrict__ deg, int* __restrict__ bsum) {
  const int i = blockIdx.x * 256 + threadIdx.x;
  int v = (i < N_NODES) ? deg[i] : 0;
#pragma unroll
  for (int o = 32; o > 0; o >>= 1) v += __shfl_down(v, o, 64);
  __shared__ int ws[4];
  if ((threadIdx.x & 63) == 0) ws[threadIdx.x >> 6] = v;
  __syncthreads();
  if (threadIdx.x == 0) bsum[blockIdx.x] = ws[0] + ws[1] + ws[2] + ws[3];
}

// scan the 196 block sums; also zero SUMS/CNT with idle threads
__global__ __launch_bounds__(256) void scanB_kernel(
    int* __restrict__ bsum, int* __restrict__ row_ptr,
    float* __restrict__ sums_zero, int nz) {
  __shared__ int sh[256];
  const int t = threadIdx.x;
  int v = (t < SCAN_BLOCKS) ? bsum[t] : 0;
  sh[t] = v;
  __syncthreads();
  for (int o = 1; o < 256; o <<= 1) {
    const int u = (t >= o) ? sh[t - o] : 0;
    __syncthreads();
    sh[t] += u;
    __syncthreads();
  }
  bsum[t] = (t == 0) ? 0 : sh[t - 1];   // exclusive
  if (t == 0) row_ptr[N_NODES] = N_EDGES;
  for (int i = t; i < nz; i += 256) sums_zero[i] = 0.f;
}

__global__ __launch_bounds__(256) void scanC_kernel(
    const int* __restrict__ deg, const int* __restrict__ bsum,
    int* __restrict__ row_ptr, int* __restrict__ cursor) {
  __shared__ int sh[256];
  const int t = threadIdx.x;
  const int i = blockIdx.x * 256 + t;
  const int v = (i < N_NODES) ? deg[i] : 0;
  sh[t] = v;
  __syncthreads();
  for (int o = 1; o < 256; o <<= 1) {
    const int u = (t >= o) ? sh[t - o] : 0;
    __syncthreads();
    sh[t] += u;
    __syncthreads();
  }
  if (i < N_NODES) {
    const int excl = bsum[blockIdx.x] + sh[t] - v;
    row_ptr[i] = excl;
    cursor[i] = excl;
  }
}

__global__ __launch_bounds__(256) void fill_kernel(
    const int* __restrict__ src, const int* __restrict__ dst,
    int* __restrict__ cursor, int* __restrict__ adj) {
  const int e = blockIdx.x * 256 + threadIdx.x;
  if (e < N_EDGES) {
    const int pos = atomicAdd(&cursor[dst[e]], 1);
    adj[pos] = src[e];
  }
}

// ---------------------------------------------------------------------------
// gather + fused update, float4, unroll-2: 8 lanes/node, lane owns 4 feats.
// H[n] = leaky(H[n] + sum_{k in row(n)} T[adj[k]])
// ---------------------------------------------------------------------------
__global__ __launch_bounds__(256) void gather_update_v3(
    const float* __restrict__ T, const int* __restrict__ row_ptr,
    const int* __restrict__ adj, float* __restrict__ H) {
  const int gid = blockIdx.x * 256 + threadIdx.x;
  const int n = gid >> 3;
  const int q = gid & 7;
  if (n >= N_NODES) return;
  const int lo = row_ptr[n], hi = row_ptr[n + 1];
  const float4* __restrict__ T4 = reinterpret_cast<const float4*>(T);
  float4 acc = make_float4(0.f, 0.f, 0.f, 0.f);
  int k = lo;
  for (; k + 1 < hi; k += 2) {
    const int s0 = adj[k];
    const int s1 = adj[k + 1];
    const float4 t0 = T4[s0 * 8 + q];
    const float4 t1 = T4[s1 * 8 + q];
    acc.x += t0.x + t1.x; acc.y += t0.y + t1.y;
    acc.z += t0.z + t1.z; acc.w += t0.w + t1.w;
  }
  if (k < hi) {
    const float4 t = T4[adj[k] * 8 + q];
    acc.x += t.x; acc.y += t.y; acc.z += t.z; acc.w += t.w;
  }
  float4* __restrict__ H4 = reinterpret_cast<float4*>(H);
  float4 h = H4[n * 8 + q];
  h.x += acc.x; h.y += acc.y; h.z += acc.z; h.w += acc.w;
  h.x = (h.x >= 0.f) ? h.x : NEG_SLOPE * h.x;
  h.y = (h.y >= 0.f) ? h.y : NEG_SLOPE * h.y;
  h.z = (h.z >= 0.f) ? h.z : NEG_SLOPE * h.z;
  h.w = (h.w >= 0.f) ? h.w : NEG_SLOPE * h.w;
  H4[n * 8 + q] = h;
}

// ---------------------------------------------------------------------------
// Input KAN v9 (PROVEN 59-60us; rounds 12/16): 256 thr, 128 nodes/block;
// thread = (o-quad oq, 4-node group). Per i-step: 8 w-b128 + 2 trig-b128
// per 128 FMA. Weights XOR-swizzled; trig (c1,s1) rows padded to 260.
// LDS 73.9KB -> 2 blocks/CU. FROZEN: v10 (reg-trig) 78us, v11 (o-split)
// 91us, v12 (K-split) 185us, v13 (global-W) 173us, v14 (16i-chunk) 137us
// ALL LOST — every perturbation either starves occupancy or spills.
// ---------------------------------------------------------------------------
__global__ __launch_bounds__(256, 2) void kan_input_v9(
    const float* __restrict__ X, const float* __restrict__ W,
    float* __restrict__ H) {
  extern __shared__ float smem[];
  float4* __restrict__ w4 = reinterpret_cast<float4*>(smem);   // 4096 f4
  float* __restrict__ tg = smem + 16384;                       // 8*260 floats
  const int tid = threadIdx.x;
  const int n0 = blockIdx.x * 128;

  // stage weights, swizzled: slot-in-row = i ^ ((o>>2)&7)
  const float4* __restrict__ Wg = reinterpret_cast<const float4*>(W);
#pragma unroll
  for (int r = 0; r < 16; ++r) {
    const int idx = r * 256 + tid;       // 0..4095 (cos: 0..2047, sin: 2048+)
    const int part = idx >> 11;
    const int rem = idx & 2047;
    const int o = rem >> 6;
    const int i = rem & 63;
    w4[part * 2048 + o * 64 + (i ^ ((o >> 2) & 7))] = Wg[idx];
  }

  const int oq = tid & 7;        // outputs 4*oq .. 4*oq+3
  const int grp = tid >> 3;      // 0..31 -> local nodes 4*grp .. 4*grp+3
  const int nb = 4 * grp;

  float acc[4][4];
#pragma unroll
  for (int n = 0; n < 4; ++n)
#pragma unroll
    for (int q = 0; q < 4; ++q) acc[n][q] = 0.f;

  for (int ch = 0; ch < 8; ++ch) {
    __syncthreads();   // protect tg (prev chunk readers) + first-iter staging
    // phase 1: (c1,s1) for 128 nodes x 8 i
#pragma unroll
    for (int p = 0; p < 4; ++p) {
      const int lin = p * 256 + tid;
      const int il = lin & 7;
      const int node = lin >> 3;     // 0..127
      const int gn = n0 + node;
      const int gs = (gn < N_NODES) ? gn : (N_NODES - 1);
      const float v = X[gs * IN_FEAT + ch * 8 + il];
      float s1, c1;
      sincosf(v, &s1, &c1);
      *reinterpret_cast<float2*>(&tg[il * 260 + node * 2]) = make_float2(c1, s1);
    }
    __syncthreads();
    // phase 2
#pragma unroll
    for (int il = 0; il < 8; ++il) {
      const int i = ch * 8 + il;
      const float4 tA = *reinterpret_cast<const float4*>(&tg[il * 260 + nb * 2]);
      const float4 tB = *reinterpret_cast<const float4*>(&tg[il * 260 + nb * 2 + 4]);
      const float bc[4] = {tA.x, tA.z, tB.x, tB.z};
      const float bs[4] = {tA.y, tA.w, tB.y, tB.w};
      float cN[4][4], sN[4][4];
#pragma unroll
      for (int n = 0; n < 4; ++n) {
        const float c1 = bc[n], s1 = bs[n];
        const float c2 = c1*c1 - s1*s1, s2 = s1*c1 + c1*s1;
        const float c3 = c2*c1 - s2*s1, s3 = s2*c1 + c2*s1;
        const float c4 = c3*c1 - s3*s1, s4 = s3*c1 + c3*s1;
        cN[n][0]=c1; cN[n][1]=c2; cN[n][2]=c3; cN[n][3]=c4;
        sN[n][0]=s1; sN[n][1]=s2; sN[n][2]=s3; sN[n][3]=s4;
      }
      const int sl = i ^ oq;
#pragma unroll
      for (int q = 0; q < 4; ++q) {
        const float4 a = w4[(4 * oq + q) * 64 + sl];
        const float4 b = w4[2048 + (4 * oq + q) * 64 + sl];
#pragma unroll
        for (int n = 0; n < 4; ++n)
          acc[n][q] += cN[n][0]*a.x + cN[n][1]*a.y + cN[n][2]*a.z + cN[n][3]*a.w
                     + sN[n][0]*b.x + sN[n][1]*b.y + sN[n][2]*b.z + sN[n][3]*b.w;
      }
    }
  }
#pragma unroll
  for (int n = 0; n < 4; ++n) {
    const int gn = n0 + nb + n;
    if (gn < N_NODES)
      *reinterpret_cast<float4*>(&H[gn * HIDDEN + 4 * oq]) =
          make_float4(acc[n][0], acc[n][1], acc[n][2], acc[n][3]);
  }
}

// ---------------------------------------------------------------------------
// Conv KAN v9 (PROVEN @ rounds 12/16): same structure; 32 i un-chunked.
// LDS 64.5KB -> 2 blocks/CU. FROZEN.
// ---------------------------------------------------------------------------
__global__ __launch_bounds__(256, 2) void kan_node_v9(
    const float* __restrict__ Hin, const float* __restrict__ W,
    float* __restrict__ T) {
  extern __shared__ float smem[];
  float4* __restrict__ w4 = reinterpret_cast<float4*>(smem);   // 2048 f4
  float* __restrict__ tg = smem + 8192;                        // 32*260 floats
  const int tid = threadIdx.x;
  const int n0 = blockIdx.x * 128;

  const float4* __restrict__ Wg = reinterpret_cast<const float4*>(W);
#pragma unroll
  for (int r = 0; r < 8; ++r) {
    const int idx = r * 256 + tid;       // 0..2047
    const int part = idx >> 10;
    const int rem = idx & 1023;
    const int o = rem >> 5;
    const int i = rem & 31;
    w4[part * 1024 + o * 32 + (i ^ ((o >> 2) & 7))] = Wg[idx];
  }

  // phase 1: (c1,s1) for 128 nodes x 32 i
#pragma unroll
  for (int p = 0; p < 16; ++p) {
    const int lin = p * 256 + tid;
    const int il = lin & 31;
    const int node = lin >> 5;       // 0..127
    const int gn = n0 + node;
    const int gs = (gn < N_NODES) ? gn : (N_NODES - 1);
    const float v = Hin[gs * HIDDEN + il];
    float s1, c1;
    sincosf(v, &s1, &c1);
    *reinterpret_cast<float2*>(&tg[il * 260 + node * 2]) = make_float2(c1, s1);
  }
  __syncthreads();

  const int oq = tid & 7;
  const int grp = tid >> 3;
  const int nb = 4 * grp;

  float acc[4][4];
#pragma unroll
  for (int n = 0; n < 4; ++n)
#pragma unroll
    for (int q = 0; q < 4; ++q) acc[n][q] = 0.f;

#pragma unroll 4
  for (int i = 0; i < HIDDEN; ++i) {
    const float4 tA = *reinterpret_cast<const float4*>(&tg[i * 260 + nb * 2]);
    const float4 tB = *reinterpret_cast<const float4*>(&tg[i * 260 + nb * 2 + 4]);
    const float bc[4] = {tA.x, tA.z, tB.x, tB.z};
    const float bs[4] = {tA.y, tA.w, tB.y, tB.w};
    float cN[4][4], sN[4][4];
#pragma unroll
    for (int n = 0; n < 4; ++n) {
      const float c1 = bc[n], s1 = bs[n];
      const float c2 = c1*c1 - s1*s1, s2 = s1*c1 + c1*s1;
      const float c3 = c2*c1 - s2*s1, s3 = s2*c1 + c2*s1;
      const float c4 = c3*c1 - s3*s1, s4 = s3*c1 + c3*s1;
      cN[n][0]=c1; cN[n][1]=c2; cN[n][2]=c3; cN[n][3]=c4;
      sN[n][0]=s1; sN[n][1]=s2; sN[n][2]=s3; sN[n][3]=s4;
    }
    const int sl = i ^ oq;
#pragma unroll
    for (int q = 0; q < 4; ++q) {
      const float4 a = w4[(4 * oq + q) * 32 + sl];
      const float4 b = w4[1024 + (4 * oq + q) * 32 + sl];
#pragma unroll
      for (int n = 0; n < 4; ++n)
        acc[n][q] += cN[n][0]*a.x + cN[n][1]*a.y + cN[n][2]*a.z + cN[n][3]*a.w
                   + sN[n][0]*b.x + sN[n][1]*b.y + sN[n][2]*b.z + sN[n][3]*b.w;
    }
  }
#pragma unroll
  for (int n = 0; n < 4; ++n) {
    const int gn = n0 + nb + n;
    if (gn < N_NODES)
      *reinterpret_cast<float4*>(&T[gn * HIDDEN + 4 * oq]) =
          make_float4(acc[n][0], acc[n][1], acc[n][2], acc[n][3]);
  }
}

// ---------------------------------------------------------------------------
// pool via run-length over sorted batch
// ---------------------------------------------------------------------------
#define POOL_RANGES 2048
__global__ __launch_bounds__(256) void pool_rl(
    const float* __restrict__ H, const int* __restrict__ batch,
    float* __restrict__ sums, float* __restrict__ cnt) {
  const int tid = threadIdx.x;
  const int f = tid & 31;
  const int r = blockIdx.x * 8 + (tid >> 5);
  const int PER = (N_NODES + POOL_RANGES - 1) / POOL_RANGES;  // 25
  int n = r * PER;
  const int end = (n + PER < N_NODES) ? n + PER : N_NODES;
  if (n >= end) return;
  int g = batch[n];
  float acc = 0.f, c = 0.f;
  for (; n < end; ++n) {
    const int gn = batch[n];
    if (gn != g) {
      atomicAdd(&sums[g * HIDDEN + f], acc);
      if (f == 0) atomicAdd(&cnt[g], c);
      g = gn; acc = 0.f; c = 0.f;
    }
    acc += H[n * HIDDEN + f];
    c += 1.f;
  }
  atomicAdd(&sums[g * HIDDEN + f], acc);
  if (f == 0) atomicAdd(&cnt[g], c);
}

// ---------------------------------------------------------------------------
__global__ __launch_bounds__(128) void readout_kernel(
    const float* __restrict__ sums, const float* __restrict__ cnt,
    const float* __restrict__ Wout, const float* __restrict__ bout,
    float* __restrict__ out) {
  const int g = threadIdx.x;
  if (g < N_GRAPHS) {
    const float c = fmaxf(cnt[g], 1.0f);
    float z = 0.f;
#pragma unroll
    for (int i = 0; i < HIDDEN; ++i) {
      const float y = sums[g * HIDDEN + i] / c;
      z += cosf(y) * Wout[i] + sinf(y) * Wout[HIDDEN + i];
    }
    z += bout[0];
    out[g] = 1.0f / (1.0f + expf(-z));
  }
}

// ---------------------------------------------------------------------------
extern "C" void kernel_launch(void* const* d_in, const int* in_sizes, int n_in,
                              void* d_out, int out_size, void* d_ws, size_t ws_size,
                              hipStream_t stream) {
  const float* x        = (const float*)d_in[0];
  const int*   eidx     = (const int*)d_in[1];
  const int*   batch    = (const int*)d_in[2];
  const float* W_in     = (const float*)d_in[3];
  const float* W_conv   = (const float*)d_in[4];
  const float* W_out    = (const float*)d_in[5];
  const float* b_out    = (const float*)d_in[6];
  float* out            = (float*)d_out;

  const int* src = eidx;            // edge_index[0]
  const int* dst = eidx + N_EDGES;  // edge_index[1]

  float* ws = (float*)d_ws;
  float* H       = ws;                         // 1.6M floats
  float* T       = ws + NH;                    // 1.6M floats
  int*   row_ptr = (int*)(ws + 2 * NH);        // 50001 (pad 50008)
  int*   deg     = row_ptr + 50008;            // 50000 (pad 50048)
  int*   cursor  = deg + 50048;                // 50000 (pad 50048)
  int*   bsum    = cursor + 50048;             // 256
  int*   adj     = bsum + 256;                 // 800000
  float* SUMS    = (float*)(adj + 800000);     // 4096
  float* CNT     = SUMS + 4096;                // 128

  const int kan_blocks  = (N_NODES + 127) / 128;     // 391
  const int edge_blocks = (N_EDGES + 255) / 256;     // 3125
  const int gath_blocks = (N_NODES * 8 + 255) / 256; // 1563

  const size_t in_lds   = (size_t)(16384 + 8 * 260) * 4;   // 73856 B (2/CU)
  const size_t conv_lds = (size_t)(8192 + 32 * 260) * 4;   // 66048 B (2/CU)
  const int WCONV_STRIDE = 2 * HIDDEN * HIDDEN * GRID_SZ;  // 8192

  // --- CSR build (multi-block scan; every kernel chip-wide)
  zero_int_kernel<<<SCAN_BLOCKS, 256, 0, stream>>>(deg, N_NODES);
  hist_kernel<<<edge_blocks, 256, 0, stream>>>(dst, deg);
  scanA_kernel<<<SCAN_BLOCKS, 256, 0, stream>>>(deg, bsum);
  scanB_kernel<<<1, 256, 0, stream>>>(bsum, row_ptr, SUMS, N_GRAPHS * HIDDEN + N_GRAPHS);
  scanC_kernel<<<SCAN_BLOCKS, 256, 0, stream>>>(deg, bsum, row_ptr, cursor);
  fill_kernel<<<edge_blocks, 256, 0, stream>>>(src, dst, cursor, adj);

  // --- input KAN projection: H = KAN_in(x)
  kan_input_v9<<<kan_blocks, 256, in_lds, stream>>>(x, W_in, H);

  // --- layer 0: T = KAN_0(H); H = leaky(H + gather(T))
  kan_node_v9<<<kan_blocks, 256, conv_lds, stream>>>(H, W_conv, T);
  gather_update_v3<<<gath_blocks, 256, 0, stream>>>(T, row_ptr, adj, H);

  // --- layer 1
  kan_node_v9<<<kan_blocks, 256, conv_lds, stream>>>(H, W_conv + WCONV_STRIDE, T);
  gather_update_v3<<<gath_blocks, 256, 0, stream>>>(T, row_ptr, adj, H);

  // --- pool + readout
  pool_rl<<<POOL_RANGES / 8, 256, 0, stream>>>(H, batch, SUMS, CNT);
  readout_kernel<<<1, 128, 0, stream>>>(SUMS, CNT, W_out, b_out, out);
}

// Round 21
// 266.474 us; speedup vs baseline: 1.8220x; 1.0350x over previous
//
#include <hip/hip_runtime.h>
#include <math.h>

#define N_NODES   50000
#define N_EDGES   800000
#define IN_FEAT   64
#define HIDDEN    32
#define GRID_SZ   4
#define N_GRAPHS  128
#define NEG_SLOPE 0.01f
#define SCAN_BLOCKS 196   // ceil(50000/256)
#define NH (N_NODES * HIDDEN)   // 1.6M

// ---------------------------------------------------------------------------
// CSR build
// ---------------------------------------------------------------------------
__global__ __launch_bounds__(256) void hist_kernel(
    const int* __restrict__ dst, int* __restrict__ deg) {
  const int e = blockIdx.x * 256 + threadIdx.x;
  if (e < N_EDGES) atomicAdd(&deg[dst[e]], 1);
}

__global__ __launch_bounds__(256) void scanA_kernel(
    const int* __restrict__ deg, int* __restrict__ bsum) {
  const int i = blockIdx.x * 256 + threadIdx.x;
  int v = (i < N_NODES) ? deg[i] : 0;
#pragma unroll
  for (int o = 32; o > 0; o >>= 1) v += __shfl_down(v, o, 64);
  __shared__ int ws[4];
  if ((threadIdx.x & 63) == 0) ws[threadIdx.x >> 6] = v;
  __syncthreads();
  if (threadIdx.x == 0) bsum[blockIdx.x] = ws[0] + ws[1] + ws[2] + ws[3];
}

// scan the 196 block sums; also zero SUMS/CNT with idle threads
__global__ __launch_bounds__(256) void scanB_kernel(
    int* __restrict__ bsum, int* __restrict__ row_ptr,
    float* __restrict__ sums_zero, int nz) {
  __shared__ int sh[256];
  const int t = threadIdx.x;
  int v = (t < SCAN_BLOCKS) ? bsum[t] : 0;
  sh[t] = v;
  __syncthreads();
  for (int o = 1; o < 256; o <<= 1) {
    const int u = (t >= o) ? sh[t - o] : 0;
    __syncthreads();
    sh[t] += u;
    __syncthreads();
  }
  bsum[t] = (t == 0) ? 0 : sh[t - 1];   // exclusive
  if (t == 0) row_ptr[N_NODES] = N_EDGES;
  for (int i = t; i < nz; i += 256) sums_zero[i] = 0.f;
}

__global__ __launch_bounds__(256) void scanC_kernel(
    const int* __restrict__ deg, const int* __restrict__ bsum,
    int* __restrict__ row_ptr, int* __restrict__ cursor) {
  __shared__ int sh[256];
  const int t = threadIdx.x;
  const int i = blockIdx.x * 256 + t;
  const int v = (i < N_NODES) ? deg[i] : 0;
  sh[t] = v;
  __syncthreads();
  for (int o = 1; o < 256; o <<= 1) {
    const int u = (t >= o) ? sh[t - o] : 0;
    __syncthreads();
    sh[t] += u;
    __syncthreads();
  }
  if (i < N_NODES) {
    const int excl = bsum[blockIdx.x] + sh[t] - v;
    row_ptr[i] = excl;
    cursor[i] = excl;
  }
}

__global__ __launch_bounds__(256) void fill_kernel(
    const int* __restrict__ src, const int* __restrict__ dst,
    int* __restrict__ cursor, int* __restrict__ adj) {
  const int e = blockIdx.x * 256 + threadIdx.x;
  if (e < N_EDGES) {
    const int pos = atomicAdd(&cursor[dst[e]], 1);
    adj[pos] = src[e];
  }
}

// ---------------------------------------------------------------------------
// gather + fused update, float4, unroll-2: 8 lanes/node, lane owns 4 feats.
// H[n] = leaky(H[n] + sum_{k in row(n)} T[adj[k]])
// ---------------------------------------------------------------------------
__global__ __launch_bounds__(256) void gather_update_v3(
    const float* __restrict__ T, const int* __restrict__ row_ptr,
    const int* __restrict__ adj, float* __restrict__ H) {
  const int gid = blockIdx.x * 256 + threadIdx.x;
  const int n = gid >> 3;
  const int q = gid & 7;
  if (n >= N_NODES) return;
  const int lo = row_ptr[n], hi = row_ptr[n + 1];
  const float4* __restrict__ T4 = reinterpret_cast<const float4*>(T);
  float4 acc = make_float4(0.f, 0.f, 0.f, 0.f);
  int k = lo;
  for (; k + 1 < hi; k += 2) {
    const int s0 = adj[k];
    const int s1 = adj[k + 1];
    const float4 t0 = T4[s0 * 8 + q];
    const float4 t1 = T4[s1 * 8 + q];
    acc.x += t0.x + t1.x; acc.y += t0.y + t1.y;
    acc.z += t0.z + t1.z; acc.w += t0.w + t1.w;
  }
  if (k < hi) {
    const float4 t = T4[adj[k] * 8 + q];
    acc.x += t.x; acc.y += t.y; acc.z += t.z; acc.w += t.w;
  }
  float4* __restrict__ H4 = reinterpret_cast<float4*>(H);
  float4 h = H4[n * 8 + q];
  h.x += acc.x; h.y += acc.y; h.z += acc.z; h.w += acc.w;
  h.x = (h.x >= 0.f) ? h.x : NEG_SLOPE * h.x;
  h.y = (h.y >= 0.f) ? h.y : NEG_SLOPE * h.y;
  h.z = (h.z >= 0.f) ? h.z : NEG_SLOPE * h.z;
  h.w = (h.w >= 0.f) ? h.w : NEG_SLOPE * h.w;
  H4[n * 8 + q] = h;
}

// ---------------------------------------------------------------------------
// Input KAN v9 (PROVEN 58-60us; rounds 12/16/20): FROZEN.
// v10 (reg-trig) 78us, v11 (o-split) 91us, v12 (K-split) 185us,
// v13 (global-W) 173us, v14 (16i-chunk) 137us ALL LOST — every
// perturbation either starves occupancy or spills past VGPR 116.
// ---------------------------------------------------------------------------
__global__ __launch_bounds__(256, 2) void kan_input_v9(
    const float* __restrict__ X, const float* __restrict__ W,
    float* __restrict__ H) {
  extern __shared__ float smem[];
  float4* __restrict__ w4 = reinterpret_cast<float4*>(smem);   // 4096 f4
  float* __restrict__ tg = smem + 16384;                       // 8*260 floats
  const int tid = threadIdx.x;
  const int n0 = blockIdx.x * 128;

  // stage weights, swizzled: slot-in-row = i ^ ((o>>2)&7)
  const float4* __restrict__ Wg = reinterpret_cast<const float4*>(W);
#pragma unroll
  for (int r = 0; r < 16; ++r) {
    const int idx = r * 256 + tid;       // 0..4095 (cos: 0..2047, sin: 2048+)
    const int part = idx >> 11;
    const int rem = idx & 2047;
    const int o = rem >> 6;
    const int i = rem & 63;
    w4[part * 2048 + o * 64 + (i ^ ((o >> 2) & 7))] = Wg[idx];
  }

  const int oq = tid & 7;        // outputs 4*oq .. 4*oq+3
  const int grp = tid >> 3;      // 0..31 -> local nodes 4*grp .. 4*grp+3
  const int nb = 4 * grp;

  float acc[4][4];
#pragma unroll
  for (int n = 0; n < 4; ++n)
#pragma unroll
    for (int q = 0; q < 4; ++q) acc[n][q] = 0.f;

  for (int ch = 0; ch < 8; ++ch) {
    __syncthreads();   // protect tg (prev chunk readers) + first-iter staging
    // phase 1: (c1,s1) for 128 nodes x 8 i
#pragma unroll
    for (int p = 0; p < 4; ++p) {
      const int lin = p * 256 + tid;
      const int il = lin & 7;
      const int node = lin >> 3;     // 0..127
      const int gn = n0 + node;
      const int gs = (gn < N_NODES) ? gn : (N_NODES - 1);
      const float v = X[gs * IN_FEAT + ch * 8 + il];
      float s1, c1;
      sincosf(v, &s1, &c1);
      *reinterpret_cast<float2*>(&tg[il * 260 + node * 2]) = make_float2(c1, s1);
    }
    __syncthreads();
    // phase 2
#pragma unroll
    for (int il = 0; il < 8; ++il) {
      const int i = ch * 8 + il;
      const float4 tA = *reinterpret_cast<const float4*>(&tg[il * 260 + nb * 2]);
      const float4 tB = *reinterpret_cast<const float4*>(&tg[il * 260 + nb * 2 + 4]);
      const float bc[4] = {tA.x, tA.z, tB.x, tB.z};
      const float bs[4] = {tA.y, tA.w, tB.y, tB.w};
      float cN[4][4], sN[4][4];
#pragma unroll
      for (int n = 0; n < 4; ++n) {
        const float c1 = bc[n], s1 = bs[n];
        const float c2 = c1*c1 - s1*s1, s2 = s1*c1 + c1*s1;
        const float c3 = c2*c1 - s2*s1, s3 = s2*c1 + c2*s1;
        const float c4 = c3*c1 - s3*s1, s4 = s3*c1 + c3*s1;
        cN[n][0]=c1; cN[n][1]=c2; cN[n][2]=c3; cN[n][3]=c4;
        sN[n][0]=s1; sN[n][1]=s2; sN[n][2]=s3; sN[n][3]=s4;
      }
      const int sl = i ^ oq;
#pragma unroll
      for (int q = 0; q < 4; ++q) {
        const float4 a = w4[(4 * oq + q) * 64 + sl];
        const float4 b = w4[2048 + (4 * oq + q) * 64 + sl];
#pragma unroll
        for (int n = 0; n < 4; ++n)
          acc[n][q] += cN[n][0]*a.x + cN[n][1]*a.y + cN[n][2]*a.z + cN[n][3]*a.w
                     + sN[n][0]*b.x + sN[n][1]*b.y + sN[n][2]*b.z + sN[n][3]*b.w;
      }
    }
  }
#pragma unroll
  for (int n = 0; n < 4; ++n) {
    const int gn = n0 + nb + n;
    if (gn < N_NODES)
      *reinterpret_cast<float4*>(&H[gn * HIDDEN + 4 * oq]) =
          make_float4(acc[n][0], acc[n][1], acc[n][2], acc[n][3]);
  }
}

// ---------------------------------------------------------------------------
// Conv KAN v9 (PROVEN @ rounds 12/16/20): FROZEN.
// ---------------------------------------------------------------------------
__global__ __launch_bounds__(256, 2) void kan_node_v9(
    const float* __restrict__ Hin, const float* __restrict__ W,
    float* __restrict__ T) {
  extern __shared__ float smem[];
  float4* __restrict__ w4 = reinterpret_cast<float4*>(smem);   // 2048 f4
  float* __restrict__ tg = smem + 8192;                        // 32*260 floats
  const int tid = threadIdx.x;
  const int n0 = blockIdx.x * 128;

  const float4* __restrict__ Wg = reinterpret_cast<const float4*>(W);
#pragma unroll
  for (int r = 0; r < 8; ++r) {
    const int idx = r * 256 + tid;       // 0..2047
    const int part = idx >> 10;
    const int rem = idx & 1023;
    const int o = rem >> 5;
    const int i = rem & 31;
    w4[part * 1024 + o * 32 + (i ^ ((o >> 2) & 7))] = Wg[idx];
  }

  // phase 1: (c1,s1) for 128 nodes x 32 i
#pragma unroll
  for (int p = 0; p < 16; ++p) {
    const int lin = p * 256 + tid;
    const int il = lin & 31;
    const int node = lin >> 5;       // 0..127
    const int gn = n0 + node;
    const int gs = (gn < N_NODES) ? gn : (N_NODES - 1);
    const float v = Hin[gs * HIDDEN + il];
    float s1, c1;
    sincosf(v, &s1, &c1);
    *reinterpret_cast<float2*>(&tg[il * 260 + node * 2]) = make_float2(c1, s1);
  }
  __syncthreads();

  const int oq = tid & 7;
  const int grp = tid >> 3;
  const int nb = 4 * grp;

  float acc[4][4];
#pragma unroll
  for (int n = 0; n < 4; ++n)
#pragma unroll
    for (int q = 0; q < 4; ++q) acc[n][q] = 0.f;

#pragma unroll 4
  for (int i = 0; i < HIDDEN; ++i) {
    const float4 tA = *reinterpret_cast<const float4*>(&tg[i * 260 + nb * 2]);
    const float4 tB = *reinterpret_cast<const float4*>(&tg[i * 260 + nb * 2 + 4]);
    const float bc[4] = {tA.x, tA.z, tB.x, tB.z};
    const float bs[4] = {tA.y, tA.w, tB.y, tB.w};
    float cN[4][4], sN[4][4];
#pragma unroll
    for (int n = 0; n < 4; ++n) {
      const float c1 = bc[n], s1 = bs[n];
      const float c2 = c1*c1 - s1*s1, s2 = s1*c1 + c1*s1;
      const float c3 = c2*c1 - s2*s1, s3 = s2*c1 + c2*s1;
      const float c4 = c3*c1 - s3*s1, s4 = s3*c1 + c3*s1;
      cN[n][0]=c1; cN[n][1]=c2; cN[n][2]=c3; cN[n][3]=c4;
      sN[n][0]=s1; sN[n][1]=s2; sN[n][2]=s3; sN[n][3]=s4;
    }
    const int sl = i ^ oq;
#pragma unroll
    for (int q = 0; q < 4; ++q) {
      const float4 a = w4[(4 * oq + q) * 32 + sl];
      const float4 b = w4[1024 + (4 * oq + q) * 32 + sl];
#pragma unroll
      for (int n = 0; n < 4; ++n)
        acc[n][q] += cN[n][0]*a.x + cN[n][1]*a.y + cN[n][2]*a.z + cN[n][3]*a.w
                   + sN[n][0]*b.x + sN[n][1]*b.y + sN[n][2]*b.z + sN[n][3]*b.w;
    }
  }
#pragma unroll
  for (int n = 0; n < 4; ++n) {
    const int gn = n0 + nb + n;
    if (gn < N_NODES)
      *reinterpret_cast<float4*>(&T[gn * HIDDEN + 4 * oq]) =
          make_float4(acc[n][0], acc[n][1], acc[n][2], acc[n][3]);
  }
}

// ---------------------------------------------------------------------------
// pool via run-length over sorted batch
// ---------------------------------------------------------------------------
#define POOL_RANGES 2048
__global__ __launch_bounds__(256) void pool_rl(
    const float* __restrict__ H, const int* __restrict__ batch,
    float* __restrict__ sums, float* __restrict__ cnt) {
  const int tid = threadIdx.x;
  const int f = tid & 31;
  const int r = blockIdx.x * 8 + (tid >> 5);
  const int PER = (N_NODES + POOL_RANGES - 1) / POOL_RANGES;  // 25
  int n = r * PER;
  const int end = (n + PER < N_NODES) ? n + PER : N_NODES;
  if (n >= end) return;
  int g = batch[n];
  float acc = 0.f, c = 0.f;
  for (; n < end; ++n) {
    const int gn = batch[n];
    if (gn != g) {
      atomicAdd(&sums[g * HIDDEN + f], acc);
      if (f == 0) atomicAdd(&cnt[g], c);
      g = gn; acc = 0.f; c = 0.f;
    }
    acc += H[n * HIDDEN + f];
    c += 1.f;
  }
  atomicAdd(&sums[g * HIDDEN + f], acc);
  if (f == 0) atomicAdd(&cnt[g], c);
}

// ---------------------------------------------------------------------------
// parallel readout: thread (g, i) computes one (feature) term, 32-lane
// shuffle reduce, lane 0 applies bias + sigmoid. 4096 threads = 16 blocks.
// ---------------------------------------------------------------------------
__global__ __launch_bounds__(256) void readout_v2(
    const float* __restrict__ sums, const float* __restrict__ cnt,
    const float* __restrict__ Wout, const float* __restrict__ bout,
    float* __restrict__ out) {
  const int gid = blockIdx.x * 256 + threadIdx.x;
  const int g = gid >> 5;
  const int i = gid & 31;
  if (g >= N_GRAPHS) return;
  const float c = fmaxf(cnt[g], 1.0f);
  const float y = sums[g * HIDDEN + i] / c;
  float z = cosf(y) * Wout[i] + sinf(y) * Wout[HIDDEN + i];
#pragma unroll
  for (int o = 16; o > 0; o >>= 1) z += __shfl_down(z, o, 32);
  if (i == 0) out[g] = 1.0f / (1.0f + expf(-(z + bout[0])));
}

// ---------------------------------------------------------------------------
extern "C" void kernel_launch(void* const* d_in, const int* in_sizes, int n_in,
                              void* d_out, int out_size, void* d_ws, size_t ws_size,
                              hipStream_t stream) {
  const float* x        = (const float*)d_in[0];
  const int*   eidx     = (const int*)d_in[1];
  const int*   batch    = (const int*)d_in[2];
  const float* W_in     = (const float*)d_in[3];
  const float* W_conv   = (const float*)d_in[4];
  const float* W_out    = (const float*)d_in[5];
  const float* b_out    = (const float*)d_in[6];
  float* out            = (float*)d_out;

  const int* src = eidx;            // edge_index[0]
  const int* dst = eidx + N_EDGES;  // edge_index[1]

  float* ws = (float*)d_ws;
  float* H       = ws;                         // 1.6M floats
  float* T       = ws + NH;                    // 1.6M floats
  int*   row_ptr = (int*)(ws + 2 * NH);        // 50001 (pad 50008)
  int*   deg     = row_ptr + 50008;            // 50000 (pad 50048)
  int*   cursor  = deg + 50048;                // 50000 (pad 50048)
  int*   bsum    = cursor + 50048;             // 256
  int*   adj     = bsum + 256;                 // 800000
  float* SUMS    = (float*)(adj + 800000);     // 4096
  float* CNT     = SUMS + 4096;                // 128

  const int kan_blocks  = (N_NODES + 127) / 128;     // 391
  const int edge_blocks = (N_EDGES + 255) / 256;     // 3125
  const int gath_blocks = (N_NODES * 8 + 255) / 256; // 1563

  const size_t in_lds   = (size_t)(16384 + 8 * 260) * 4;   // 73856 B (2/CU)
  const size_t conv_lds = (size_t)(8192 + 32 * 260) * 4;   // 66048 B (2/CU)
  const int WCONV_STRIDE = 2 * HIDDEN * HIDDEN * GRID_SZ;  // 8192

  // --- CSR build (deg zeroed via async memset; multi-block scan)
  hipMemsetAsync(deg, 0, (size_t)N_NODES * sizeof(int), stream);
  hist_kernel<<<edge_blocks, 256, 0, stream>>>(dst, deg);
  scanA_kernel<<<SCAN_BLOCKS, 256, 0, stream>>>(deg, bsum);
  scanB_kernel<<<1, 256, 0, stream>>>(bsum, row_ptr, SUMS, N_GRAPHS * HIDDEN + N_GRAPHS);
  scanC_kernel<<<SCAN_BLOCKS, 256, 0, stream>>>(deg, bsum, row_ptr, cursor);
  fill_kernel<<<edge_blocks, 256, 0, stream>>>(src, dst, cursor, adj);

  // --- input KAN projection: H = KAN_in(x)
  kan_input_v9<<<kan_blocks, 256, in_lds, stream>>>(x, W_in, H);

  // --- layer 0: T = KAN_0(H); H = leaky(H + gather(T))
  kan_node_v9<<<kan_blocks, 256, conv_lds, stream>>>(H, W_conv, T);
  gather_update_v3<<<gath_blocks, 256, 0, stream>>>(T, row_ptr, adj, H);

  // --- layer 1
  kan_node_v9<<<kan_blocks, 256, conv_lds, stream>>>(H, W_conv + WCONV_STRIDE, T);
  gather_update_v3<<<gath_blocks, 256, 0, stream>>>(T, row_ptr, adj, H);

  // --- pool + readout
  pool_rl<<<POOL_RANGES / 8, 256, 0, stream>>>(H, batch, SUMS, CNT);
  readout_v2<<<(N_GRAPHS * 32 + 255) / 256, 256, 0, stream>>>(SUMS, CNT, W_out, b_out, out);
}